// Round 3
// baseline (1021.822 us; speedup 1.0000x reference)
//
#include <hip/hip_runtime.h>

#define N_NODES 50000
#define N_EDGES 1600000
#define MERGED  153
#define NPB     16
#define EPSV    1e-8f
#define STRIDE  16   // floats per node accumulator record -> 64B, one cache line

__device__ __forceinline__ float sigmoidf_(float x) { return 1.0f / (1.0f + __expf(-x)); }

// ---------------------------------------------------------------------------
// Kernel 1: scatter-mean prep with XCD-privatized accumulators.
// acc[copy][node][16] : [0..8] = sum of frames, [9] = degree.
// copy = blockIdx & copy_mask; with round-robin block->XCD dispatch each copy
// stays resident in a single XCD's L2, eliminating cross-XCD line ping-pong
// (round-1 counters: 500 MB WRITE_SIZE for a 2 MB accumulator).
// ---------------------------------------------------------------------------
__global__ __launch_bounds__(256) void scatter_frames_kernel(
    const float* __restrict__ frames,
    const int* __restrict__ row,
    float* __restrict__ acc,
    int copy_mask) {
    int e = blockIdx.x * 256 + threadIdx.x;
    if (e >= N_EDGES) return;
    int r = row[e];
    float* dst = acc + ((size_t)(blockIdx.x & copy_mask) * N_NODES + r) * STRIDE;
    const float* f = frames + (size_t)e * 9;
#pragma unroll
    for (int k = 0; k < 9; k++) atomicAdd(&dst[k], f[k]);
    atomicAdd(&dst[9], 1.0f);
}

// ---------------------------------------------------------------------------
// Kernel 2: all per-node algebra. 16 nodes per 256-thread block.
// Copy-merge of the privatized accumulators is folded into phase 1a.
// ---------------------------------------------------------------------------
__global__ __launch_bounds__(256) void node_kernel(
    const float* __restrict__ s,
    const float* __restrict__ v,
    const float* __restrict__ W_vd,
    const float* __restrict__ W_vdf,
    const float* __restrict__ W_so,
    const float* __restrict__ b_so,
    const float* __restrict__ W_vu,
    const float* __restrict__ W_vosf,
    const float* __restrict__ b_vosf,
    const float* __restrict__ W_vuf,
    const float* __restrict__ acc,
    int ncopy,
    float* __restrict__ out0,
    float* __restrict__ out1)
{
    __shared__ float vL[NPB][48];        // v[n][i][c]
    __shared__ float vhL[NPB][3][16];    // vh[c][h]
    __shared__ __align__(16) float mergedL[NPB][160];  // [s(128)|vnorm(16)|sh(9)|pad]
    __shared__ float tmpL[NPB][10];      // merged accumulator record (Fsum9 + deg)
    __shared__ float FbarL[NPB][9];      // mean frame [i*3+j]
    __shared__ float vdfL[NPB][9];       // vdf[j][c] at [j*3+c]
    __shared__ float sigL[NPB][128];     // sigmoid(scalar_rep)
    __shared__ float gateL[NPB][12];     // gate[9], padded

    const int t = threadIdx.x;
    const int base = blockIdx.x * NPB;

    // ---- phase 1a: stage v and s into LDS; merge privatized accumulators ----
    {
        int nn = t >> 4, h = t & 15;
        int n = base + nn;
#pragma unroll
        for (int r = 0; r < 3; r++) vL[nn][h * 3 + r] = v[(size_t)n * 48 + h * 3 + r];
#pragma unroll
        for (int r = 0; r < 8; r++) mergedL[nn][h * 8 + r] = s[(size_t)n * 128 + h * 8 + r];
    }
    if (t < NPB * 10) {
        int nn = t / 10, h = t % 10;
        int n = base + nn;
        float a = 0.f;
        for (int c = 0; c < ncopy; c++)
            a += acc[((size_t)c * N_NODES + n) * STRIDE + h];
        tmpL[nn][h] = a;
    }
    __syncthreads();

    // ---- phase 1b: vh, vnorm, Fbar, vdf ----
    {
        int nn = t >> 4, h = t & 15;
        float vh0 = 0.f, vh1 = 0.f, vh2 = 0.f;
#pragma unroll
        for (int i = 0; i < 16; i++) {
            float w = W_vd[i * 16 + h];
            vh0 += vL[nn][i * 3 + 0] * w;
            vh1 += vL[nn][i * 3 + 1] * w;
            vh2 += vL[nn][i * 3 + 2] * w;
        }
        vhL[nn][0][h] = vh0; vhL[nn][1][h] = vh1; vhL[nn][2][h] = vh2;
        mergedL[nn][128 + h] = sqrtf(vh0 * vh0 + vh1 * vh1 + vh2 * vh2 + EPSV);
        if (h < 9) {
            float inv = 1.0f / fmaxf(tmpL[nn][9], 1.0f);
            FbarL[nn][h] = tmpL[nn][h] * inv;
        }
        if (h < 3) {
            int cc = h;  // svod channel
#pragma unroll
            for (int j = 0; j < 3; j++) {
                float a = 0.f;
#pragma unroll
                for (int i = 0; i < 16; i++) a += vL[nn][i * 3 + j] * W_vdf[i * 3 + cc];
                vdfL[nn][j * 3 + cc] = a;
            }
        }
    }
    __syncthreads();

    // ---- phase 1c: sh[c*3+i] = sum_j Fbar[i][j] * vdf[j][c]; zero-pad ----
    {
        int nn = t >> 4, h = t & 15;
        if (h < 9) {
            int c = h / 3, i = h % 3;
            float a = 0.f;
#pragma unroll
            for (int j = 0; j < 3; j++) a += FbarL[nn][i * 3 + j] * vdfL[nn][j * 3 + c];
            mergedL[nn][144 + h] = a;
        } else {
            mergedL[nn][144 + h] = 0.0f;  // pads 153..159
        }
    }
    __syncthreads();

    // ---- phase 2: scalar_rep = merged @ W_so + b_so (float4 LDS reads) ----
    {
        int o = t & 127, half = t >> 7;
        float acc8[8];
        float b = b_so[o];
#pragma unroll
        for (int q = 0; q < 8; q++) acc8[q] = b;
        for (int g = 0; g < 38; g++) {
            int k = 4 * g;
            float w0 = W_so[(k + 0) * 128 + o];
            float w1 = W_so[(k + 1) * 128 + o];
            float w2 = W_so[(k + 2) * 128 + o];
            float w3 = W_so[(k + 3) * 128 + o];
#pragma unroll
            for (int q = 0; q < 8; q++) {
                float4 m = *(const float4*)&mergedL[half + 2 * q][k];
                acc8[q] += m.x * w0 + m.y * w1 + m.z * w2 + m.w * w3;
            }
        }
        {
            float w = W_so[152 * 128 + o];
#pragma unroll
            for (int q = 0; q < 8; q++) acc8[q] += mergedL[half + 2 * q][152] * w;
        }
#pragma unroll
        for (int q = 0; q < 8; q++) {
            int nn = half + 2 * q;
            int n = base + nn;
            out0[(size_t)n * 128 + o] = fmaxf(acc8[q], 0.0f);
            sigL[nn][o] = sigmoidf_(acc8[q]);
        }
    }
    __syncthreads();

    // ---- gate = sigmoid(sr) @ W_vosf + b_vosf ----
    if (t < NPB * 9) {
        int nn = t / 9, k = t % 9;
        float a = b_vosf[k];
        for (int o = 0; o < 128; o++) a += sigL[nn][o] * W_vosf[o * 9 + k];
        gateL[nn][k] = a;
    }
    __syncthreads();

    // ---- phase 3: vector path ----
    {
        int nn = t >> 4, o = t & 15;
        int n = base + nn;
        float gv[9];
#pragma unroll
        for (int i = 0; i < 3; i++)
#pragma unroll
            for (int kk = 0; kk < 3; kk++) {
                float a = 0.f;
#pragma unroll
                for (int j = 0; j < 3; j++) a += gateL[nn][j * 3 + i] * FbarL[nn][j * 3 + kk];
                gv[i * 3 + kk] = a;
            }
        float gvr[3];
#pragma unroll
        for (int kk = 0; kk < 3; kk++) {
            float a = 0.f;
#pragma unroll
            for (int i = 0; i < 3; i++) a += gv[i * 3 + kk] * W_vuf[i * 16 + o];
            gvr[kk] = a;
        }
        float gn = sqrtf(gvr[0] * gvr[0] + gvr[1] * gvr[1] + gvr[2] * gvr[2] + EPSV);
        float sg = sigmoidf_(gn);
#pragma unroll
        for (int c = 0; c < 3; c++) {
            float a = 0.f;
#pragma unroll
            for (int h2 = 0; h2 < 16; h2++) a += vhL[nn][c][h2] * W_vu[h2 * 16 + o];
            out1[(size_t)n * 48 + o * 3 + c] = a * sg;
        }
    }
}

extern "C" void kernel_launch(void* const* d_in, const int* in_sizes, int n_in,
                              void* d_out, int out_size, void* d_ws, size_t ws_size,
                              hipStream_t stream) {
    const float* s      = (const float*)d_in[0];
    const float* v      = (const float*)d_in[1];
    const float* frames = (const float*)d_in[2];
    const float* W_vd   = (const float*)d_in[3];
    const float* W_vdf  = (const float*)d_in[4];
    const float* W_so   = (const float*)d_in[5];
    const float* b_so   = (const float*)d_in[6];
    const float* W_vu   = (const float*)d_in[7];
    const float* W_vosf = (const float*)d_in[8];
    const float* b_vosf = (const float*)d_in[9];
    const float* W_vuf  = (const float*)d_in[10];
    const int* edge_index = (const int*)d_in[11];
    // d_in[12] = node_inputs (assumed truthy, per reference)

    const size_t per_copy = (size_t)N_NODES * STRIDE * sizeof(float);  // 3.2 MB
    int ncopy = 1;
    while (ncopy < 8 && (size_t)(ncopy * 2) * per_copy <= ws_size) ncopy *= 2;

    float* acc  = (float*)d_ws;
    float* out0 = (float*)d_out;
    float* out1 = out0 + (size_t)N_NODES * 128;

    hipMemsetAsync(d_ws, 0, (size_t)ncopy * per_copy, stream);
    scatter_frames_kernel<<<(N_EDGES + 255) / 256, 256, 0, stream>>>(
        frames, edge_index, acc, ncopy - 1);
    node_kernel<<<N_NODES / NPB, 256, 0, stream>>>(
        s, v, W_vd, W_vdf, W_so, b_so, W_vu, W_vosf, b_vosf, W_vuf,
        acc, ncopy, out0, out1);
}

// Round 4
// 359.294 us; speedup vs baseline: 2.8440x; 2.8440x over previous
//
#include <hip/hip_runtime.h>

#define N_NODES 50000
#define N_EDGES 1600000
#define MERGED  153
#define NPB     16
#define EPSV    1e-8f
#define MAXCAP  96   // Poisson(32): P(deg>96) ~ 1e-18; overflow path covers the rest

__device__ __forceinline__ float sigmoidf_(float x) { return 1.0f / (1.0f + __expf(-x)); }

// ---------------------------------------------------------------------------
// Kernel 1: bucket edge ids by destination node.
// ONE returning int atomic per edge (vs 10 f32 atomics before): round-3
// counters proved every device-scope atomic is a 32B fabric write-through
// (WRITE_SIZE == n_atomics*32B exactly), throughput ~20 Gops/s. Cutting the
// op count 10x is the only lever.
// Overflow slots (slot >= cap) go through the old atomic path into Fovf.
// ---------------------------------------------------------------------------
__global__ __launch_bounds__(256) void bucket_kernel(
    const int* __restrict__ row,
    const float* __restrict__ frames,
    int* __restrict__ cursor,
    int* __restrict__ bucket,
    float* __restrict__ Fovf,
    int cap) {
    int e = blockIdx.x * 256 + threadIdx.x;
    if (e >= N_EDGES) return;
    int r = row[e];
    int slot = atomicAdd(&cursor[r], 1);
    if (slot < cap) {
        bucket[(size_t)r * cap + slot] = e;
    } else {
        const float* f = frames + (size_t)e * 9;
#pragma unroll
        for (int k = 0; k < 9; k++) atomicAdd(&Fovf[(size_t)r * 16 + k], f[k]);
    }
}

// ---------------------------------------------------------------------------
// Kernel 2: all per-node algebra. 16 nodes per 256-thread block.
// Frame reduction is a deterministic gather over the node's bucket.
// ---------------------------------------------------------------------------
__global__ __launch_bounds__(256) void node_kernel(
    const float* __restrict__ s,
    const float* __restrict__ v,
    const float* __restrict__ frames,
    const float* __restrict__ W_vd,
    const float* __restrict__ W_vdf,
    const float* __restrict__ W_so,
    const float* __restrict__ b_so,
    const float* __restrict__ W_vu,
    const float* __restrict__ W_vosf,
    const float* __restrict__ b_vosf,
    const float* __restrict__ W_vuf,
    const int* __restrict__ cursor,
    const int* __restrict__ bucket,
    const float* __restrict__ Fovf,
    int cap,
    float* __restrict__ out0,
    float* __restrict__ out1)
{
    __shared__ float vL[NPB][48];        // v[n][i][c]
    __shared__ float vhL[NPB][3][16];    // vh[c][h]
    __shared__ __align__(16) float mergedL[NPB][160];  // [s(128)|vnorm(16)|sh(9)|pad]
    __shared__ float redL[NPB][16][9];   // per-lane partial frame sums
    __shared__ float tmpL[NPB][10];      // Fsum[9] + deg
    __shared__ float FbarL[NPB][9];      // mean frame [i*3+j]
    __shared__ float vdfL[NPB][9];       // vdf[j][c] at [j*3+c]
    __shared__ float sigL[NPB][128];     // sigmoid(scalar_rep)
    __shared__ float gateL[NPB][12];     // gate[9], padded

    const int t = threadIdx.x;
    const int base = blockIdx.x * NPB;
    const int nn = t >> 4, h = t & 15;
    const int n = base + nn;

    // ---- phase 1a: stage v and s; gather-reduce this node's frames ----
    {
#pragma unroll
        for (int r = 0; r < 3; r++) vL[nn][h * 3 + r] = v[(size_t)n * 48 + h * 3 + r];
#pragma unroll
        for (int r = 0; r < 8; r++) mergedL[nn][h * 8 + r] = s[(size_t)n * 128 + h * 8 + r];

        int dg = cursor[n];
        int lim = dg < cap ? dg : cap;
        float fs[9];
#pragma unroll
        for (int k = 0; k < 9; k++) fs[k] = 0.f;
        for (int slot = h; slot < lim; slot += 16) {
            int e = bucket[(size_t)n * cap + slot];
            const float* f = frames + (size_t)e * 9;
#pragma unroll
            for (int k = 0; k < 9; k++) fs[k] += f[k];
        }
#pragma unroll
        for (int k = 0; k < 9; k++) redL[nn][h][k] = fs[k];
        if (h == 9) tmpL[nn][9] = (float)dg;
    }
    __syncthreads();

    // ---- phase 1a': tree-sum the 16 partials + overflow ----
    if (h < 9) {
        float a = Fovf[(size_t)n * 16 + h];
#pragma unroll
        for (int j = 0; j < 16; j++) a += redL[nn][j][h];
        tmpL[nn][h] = a;
    }
    __syncthreads();

    // ---- phase 1b: vh, vnorm, Fbar, vdf ----
    {
        float vh0 = 0.f, vh1 = 0.f, vh2 = 0.f;
#pragma unroll
        for (int i = 0; i < 16; i++) {
            float w = W_vd[i * 16 + h];
            vh0 += vL[nn][i * 3 + 0] * w;
            vh1 += vL[nn][i * 3 + 1] * w;
            vh2 += vL[nn][i * 3 + 2] * w;
        }
        vhL[nn][0][h] = vh0; vhL[nn][1][h] = vh1; vhL[nn][2][h] = vh2;
        mergedL[nn][128 + h] = sqrtf(vh0 * vh0 + vh1 * vh1 + vh2 * vh2 + EPSV);
        if (h < 9) {
            float inv = 1.0f / fmaxf(tmpL[nn][9], 1.0f);
            FbarL[nn][h] = tmpL[nn][h] * inv;
        }
        if (h < 3) {
            int cc = h;  // svod channel
#pragma unroll
            for (int j = 0; j < 3; j++) {
                float a = 0.f;
#pragma unroll
                for (int i = 0; i < 16; i++) a += vL[nn][i * 3 + j] * W_vdf[i * 3 + cc];
                vdfL[nn][j * 3 + cc] = a;
            }
        }
    }
    __syncthreads();

    // ---- phase 1c: sh[c*3+i] = sum_j Fbar[i][j] * vdf[j][c]; zero-pad ----
    {
        if (h < 9) {
            int c = h / 3, i = h % 3;
            float a = 0.f;
#pragma unroll
            for (int j = 0; j < 3; j++) a += FbarL[nn][i * 3 + j] * vdfL[nn][j * 3 + c];
            mergedL[nn][144 + h] = a;
        } else {
            mergedL[nn][144 + h] = 0.0f;  // pads 153..159
        }
    }
    __syncthreads();

    // ---- phase 2: scalar_rep = merged @ W_so + b_so (float4 LDS reads) ----
    {
        int o = t & 127, half = t >> 7;
        float acc8[8];
        float b = b_so[o];
#pragma unroll
        for (int q = 0; q < 8; q++) acc8[q] = b;
        for (int g = 0; g < 38; g++) {
            int k = 4 * g;
            float w0 = W_so[(k + 0) * 128 + o];
            float w1 = W_so[(k + 1) * 128 + o];
            float w2 = W_so[(k + 2) * 128 + o];
            float w3 = W_so[(k + 3) * 128 + o];
#pragma unroll
            for (int q = 0; q < 8; q++) {
                float4 m = *(const float4*)&mergedL[half + 2 * q][k];
                acc8[q] += m.x * w0 + m.y * w1 + m.z * w2 + m.w * w3;
            }
        }
        {
            float w = W_so[152 * 128 + o];
#pragma unroll
            for (int q = 0; q < 8; q++) acc8[q] += mergedL[half + 2 * q][152] * w;
        }
#pragma unroll
        for (int q = 0; q < 8; q++) {
            int qn = half + 2 * q;
            out0[(size_t)(base + qn) * 128 + o] = fmaxf(acc8[q], 0.0f);
            sigL[qn][o] = sigmoidf_(acc8[q]);
        }
    }
    __syncthreads();

    // ---- gate = sigmoid(sr) @ W_vosf + b_vosf ----
    if (t < NPB * 9) {
        int gn = t / 9, k = t % 9;
        float a = b_vosf[k];
        for (int o = 0; o < 128; o++) a += sigL[gn][o] * W_vosf[o * 9 + k];
        gateL[gn][k] = a;
    }
    __syncthreads();

    // ---- phase 3: vector path ----
    {
        int o = h;  // VO index
        float gv[9];
#pragma unroll
        for (int i = 0; i < 3; i++)
#pragma unroll
            for (int kk = 0; kk < 3; kk++) {
                float a = 0.f;
#pragma unroll
                for (int j = 0; j < 3; j++) a += gateL[nn][j * 3 + i] * FbarL[nn][j * 3 + kk];
                gv[i * 3 + kk] = a;
            }
        float gvr[3];
#pragma unroll
        for (int kk = 0; kk < 3; kk++) {
            float a = 0.f;
#pragma unroll
            for (int i = 0; i < 3; i++) a += gv[i * 3 + kk] * W_vuf[i * 16 + o];
            gvr[kk] = a;
        }
        float gn2 = sqrtf(gvr[0] * gvr[0] + gvr[1] * gvr[1] + gvr[2] * gvr[2] + EPSV);
        float sg = sigmoidf_(gn2);
#pragma unroll
        for (int c = 0; c < 3; c++) {
            float a = 0.f;
#pragma unroll
            for (int h2 = 0; h2 < 16; h2++) a += vhL[nn][c][h2] * W_vu[h2 * 16 + o];
            out1[(size_t)n * 48 + o * 3 + c] = a * sg;
        }
    }
}

extern "C" void kernel_launch(void* const* d_in, const int* in_sizes, int n_in,
                              void* d_out, int out_size, void* d_ws, size_t ws_size,
                              hipStream_t stream) {
    const float* s      = (const float*)d_in[0];
    const float* v      = (const float*)d_in[1];
    const float* frames = (const float*)d_in[2];
    const float* W_vd   = (const float*)d_in[3];
    const float* W_vdf  = (const float*)d_in[4];
    const float* W_so   = (const float*)d_in[5];
    const float* b_so   = (const float*)d_in[6];
    const float* W_vu   = (const float*)d_in[7];
    const float* W_vosf = (const float*)d_in[8];
    const float* b_vosf = (const float*)d_in[9];
    const float* W_vuf  = (const float*)d_in[10];
    const int* edge_index = (const int*)d_in[11];
    // d_in[12] = node_inputs (assumed truthy, per reference)

    // ws layout: cursor[50K int] | Fovf[50K*16 f32] | bucket[50K*CAP int]
    const size_t cursor_b = (size_t)N_NODES * sizeof(int);          // 200 KB
    const size_t fovf_b   = (size_t)N_NODES * 16 * sizeof(float);   // 3.2 MB
    int cap = 0;
    if (ws_size > cursor_b + fovf_b) {
        size_t avail = ws_size - cursor_b - fovf_b;
        size_t c = avail / ((size_t)N_NODES * sizeof(int));
        cap = (int)(c > MAXCAP ? MAXCAP : c);
    }

    int*   cursor = (int*)d_ws;
    float* Fovf   = (float*)((char*)d_ws + cursor_b);
    int*   bucket = (int*)((char*)d_ws + cursor_b + fovf_b);
    float* out0 = (float*)d_out;
    float* out1 = out0 + (size_t)N_NODES * 128;

    hipMemsetAsync(d_ws, 0, cursor_b + fovf_b, stream);
    bucket_kernel<<<(N_EDGES + 255) / 256, 256, 0, stream>>>(
        edge_index, frames, cursor, bucket, Fovf, cap);
    node_kernel<<<N_NODES / NPB, 256, 0, stream>>>(
        s, v, frames, W_vd, W_vdf, W_so, b_so, W_vu, W_vosf, b_vosf, W_vuf,
        cursor, bucket, Fovf, cap, out0, out1);
}

// Round 5
// 355.393 us; speedup vs baseline: 2.8752x; 1.0110x over previous
//
#include <hip/hip_runtime.h>

#define N_NODES 50000
#define N_EDGES 1600000
#define NPB     16
#define CAPL    96    // LDS edge-id capacity per node; overflow summed by walker
#define MSTR    164   // mergedL row stride (160 + 4 pad: breaks 16-way LDS bank conflict on A-frag reads)
#define EPSV    1e-8f

typedef float f32x4 __attribute__((ext_vector_type(4)));
typedef short s16x8 __attribute__((ext_vector_type(8)));

__device__ __forceinline__ float sigmoidf_(float x) { return 1.0f / (1.0f + __expf(-x)); }
// f32 -> bf16 bits, round-to-nearest-even
__device__ __forceinline__ short f2bf(float x) {
    unsigned u = __float_as_uint(x);
    unsigned r = (u + 0x7FFFu + ((u >> 16) & 1u)) >> 16;
    return (short)r;
}
__device__ __forceinline__ float bf2f(short h) {
    return __uint_as_float(((unsigned)(unsigned short)h) << 16);
}

// ---------------------------------------------------------------------------
// Prep: Dekker-split W_so into bf16 hi/lo, padded to 160 K-rows (rows >=153
// zeroed so the MFMA K-loop needs no bounds check).
// ---------------------------------------------------------------------------
__global__ __launch_bounds__(256) void prep_w_kernel(
    const float* __restrict__ W_so, short* __restrict__ Whi, short* __restrict__ Wlo) {
    int i = blockIdx.x * 256 + threadIdx.x;  // i = k*128 + o
    if (i >= 160 * 128) return;
    int k = i >> 7;
    float w = (k < 153) ? W_so[i] : 0.0f;
    short hh = f2bf(w);
    Whi[i] = hh;
    Wlo[i] = f2bf(w - bf2f(hh));
}

// ---------------------------------------------------------------------------
// Kernel 1: linked-list bucketing. Round-4 counters: each fabric op
// (atomic OR scattered store) costs ~32B write-through at ~20 Gops/s;
// 3.2M ops -> 140us. Here: 1 atomicExch + 1 COALESCED store per edge
// (next[] is indexed by e) -> 1.6M fabric ops.
// ---------------------------------------------------------------------------
__global__ __launch_bounds__(256) void bucket_kernel(
    const int* __restrict__ row,
    int* __restrict__ head,
    int* __restrict__ nxt) {
    int e = blockIdx.x * 256 + threadIdx.x;
    if (e >= N_EDGES) return;
    int r = row[e];
    int prev = atomicExch(&head[r], e);
    nxt[e] = prev;
}

// ---------------------------------------------------------------------------
// Kernel 2: all per-node algebra. 16 nodes per 256-thread block.
// Chain walk (16 parallel walkers) -> frame gather-reduce -> small mats ->
// phase-2 GEMM as split-bf16 MFMA (3 mfma per product = f32-class accuracy).
// ---------------------------------------------------------------------------
__global__ __launch_bounds__(256) void node_kernel(
    const float* __restrict__ s,
    const float* __restrict__ v,
    const float* __restrict__ frames,
    const float* __restrict__ W_vd,
    const float* __restrict__ W_vdf,
    const short* __restrict__ Whi,
    const short* __restrict__ Wlo,
    const float* __restrict__ b_so,
    const float* __restrict__ W_vu,
    const float* __restrict__ W_vosf,
    const float* __restrict__ b_vosf,
    const float* __restrict__ W_vuf,
    const int* __restrict__ head,
    const int* __restrict__ nxt,
    float* __restrict__ out0,
    float* __restrict__ out1)
{
    __shared__ float vL[NPB][48];
    __shared__ float vhL[NPB][3][16];
    __shared__ __align__(16) float mergedL[NPB][MSTR];  // [s(128)|vnorm(16)|sh(9)|pad0(7)]
    __shared__ int   eidL[NPB][CAPL];
    __shared__ int   degL[NPB];
    __shared__ float ovfL[NPB][9];
    __shared__ float redL[NPB][16][9];
    __shared__ float tmpL[NPB][10];      // Fsum[9] + deg
    __shared__ float FbarL[NPB][9];
    __shared__ float vdfL[NPB][9];
    __shared__ __align__(16) float sigL[NPB][128];
    __shared__ float gateL[NPB][12];

    const int t = threadIdx.x;
    const int base = blockIdx.x * NPB;
    const int nn = t >> 4, h = t & 15;
    const int n = base + nn;

    // ---- phase 0: stage v, s; 16 walkers traverse edge chains ----
#pragma unroll
    for (int r = 0; r < 3; r++) vL[nn][h * 3 + r] = v[(size_t)n * 48 + h * 3 + r];
#pragma unroll
    for (int r = 0; r < 8; r++) mergedL[nn][h * 8 + r] = s[(size_t)n * 128 + h * 8 + r];

    if (t < NPB) {
        int node = base + t;
        int cnt = 0;
        float ov[9];
#pragma unroll
        for (int k = 0; k < 9; k++) ov[k] = 0.f;
        int e = head[node];
        while (e >= 0) {
            if (cnt < CAPL) {
                eidL[t][cnt] = e;
            } else {
                const float* f = frames + (size_t)e * 9;
#pragma unroll
                for (int k = 0; k < 9; k++) ov[k] += f[k];
            }
            cnt++;
            e = nxt[e];
        }
        degL[t] = cnt;
#pragma unroll
        for (int k = 0; k < 9; k++) ovfL[t][k] = ov[k];
    }
    __syncthreads();

    // ---- frame gather-reduce: 16 lanes per node walk the id list ----
    {
        int dg = degL[nn];
        int lim = dg < CAPL ? dg : CAPL;
        float fs[9];
#pragma unroll
        for (int k = 0; k < 9; k++) fs[k] = 0.f;
        for (int slot = h; slot < lim; slot += 16) {
            int e = eidL[nn][slot];
            const float* f = frames + (size_t)e * 9;
#pragma unroll
            for (int k = 0; k < 9; k++) fs[k] += f[k];
        }
#pragma unroll
        for (int k = 0; k < 9; k++) redL[nn][h][k] = fs[k];
        if (h == 9) tmpL[nn][9] = (float)dg;
    }
    __syncthreads();
    if (h < 9) {
        float a = ovfL[nn][h];
#pragma unroll
        for (int j = 0; j < 16; j++) a += redL[nn][j][h];
        tmpL[nn][h] = a;
    }
    __syncthreads();

    // ---- phase 1b: vh, vnorm, Fbar, vdf ----
    {
        float vh0 = 0.f, vh1 = 0.f, vh2 = 0.f;
#pragma unroll
        for (int i = 0; i < 16; i++) {
            float w = W_vd[i * 16 + h];
            vh0 += vL[nn][i * 3 + 0] * w;
            vh1 += vL[nn][i * 3 + 1] * w;
            vh2 += vL[nn][i * 3 + 2] * w;
        }
        vhL[nn][0][h] = vh0; vhL[nn][1][h] = vh1; vhL[nn][2][h] = vh2;
        mergedL[nn][128 + h] = sqrtf(vh0 * vh0 + vh1 * vh1 + vh2 * vh2 + EPSV);
        if (h < 9) {
            float inv = 1.0f / fmaxf(tmpL[nn][9], 1.0f);
            FbarL[nn][h] = tmpL[nn][h] * inv;
        }
        if (h < 3) {
            int cc = h;
#pragma unroll
            for (int j = 0; j < 3; j++) {
                float a = 0.f;
#pragma unroll
                for (int i = 0; i < 16; i++) a += vL[nn][i * 3 + j] * W_vdf[i * 3 + cc];
                vdfL[nn][j * 3 + cc] = a;
            }
        }
    }
    __syncthreads();

    // ---- phase 1c: sh + zero-pad merged[144..163] ----
    {
        if (h < 9) {
            int c = h / 3, i = h % 3;
            float a = 0.f;
#pragma unroll
            for (int j = 0; j < 3; j++) a += FbarL[nn][i * 3 + j] * vdfL[nn][j * 3 + c];
            mergedL[nn][144 + h] = a;
        } else {
            mergedL[nn][144 + h] = 0.0f;  // 153..159
        }
        if (h < 4) mergedL[nn][160 + h] = 0.0f;  // stride pad
    }
    __syncthreads();

    // ---- phase 2: C[16x128] = merged[16x160] @ W_so via split-bf16 MFMA ----
    // wave w handles o in [32w, 32w+32): two 16x16 tiles, K-loop 5x32.
    // A-frag: A[m=lane&15][k=quad*8+j]; B-frag: B[k=quad*8+j][n=lane&15];
    // C/D: col=lane&15, row=quad*4+reg (m89/m91/m120-verified layouts).
    {
        const int w = t >> 6;
        const int lane = t & 63;
        const int quad = lane >> 4;
        const int col = lane & 15;
        f32x4 acc[2];
        acc[0] = (f32x4){0.f, 0.f, 0.f, 0.f};
        acc[1] = (f32x4){0.f, 0.f, 0.f, 0.f};
#pragma unroll
        for (int kk = 0; kk < 5; kk++) {
            const int krow = kk * 32 + quad * 8;
            const float* ap = &mergedL[col][krow];
            float4 a0v = *(const float4*)ap;
            float4 a1v = *(const float4*)(ap + 4);
            float av[8] = {a0v.x, a0v.y, a0v.z, a0v.w, a1v.x, a1v.y, a1v.z, a1v.w};
            s16x8 ahi, alo;
#pragma unroll
            for (int j = 0; j < 8; j++) {
                short hh = f2bf(av[j]);
                ahi[j] = hh;
                alo[j] = f2bf(av[j] - bf2f(hh));
            }
#pragma unroll
            for (int t0 = 0; t0 < 2; t0++) {
                int o = w * 32 + t0 * 16 + col;
                s16x8 bhi, blo;
#pragma unroll
                for (int j = 0; j < 8; j++) {
                    bhi[j] = Whi[(krow + j) * 128 + o];
                    blo[j] = Wlo[(krow + j) * 128 + o];
                }
                acc[t0] = __builtin_amdgcn_mfma_f32_16x16x32_bf16(ahi, bhi, acc[t0], 0, 0, 0);
                acc[t0] = __builtin_amdgcn_mfma_f32_16x16x32_bf16(ahi, blo, acc[t0], 0, 0, 0);
                acc[t0] = __builtin_amdgcn_mfma_f32_16x16x32_bf16(alo, bhi, acc[t0], 0, 0, 0);
            }
        }
        // epilogue: bias, relu -> out0, sigmoid -> sigL
#pragma unroll
        for (int t0 = 0; t0 < 2; t0++) {
            int o = w * 32 + t0 * 16 + col;
            float bso = b_so[o];
#pragma unroll
            for (int r = 0; r < 4; r++) {
                int nl = quad * 4 + r;
                float val = acc[t0][r] + bso;
                out0[(size_t)(base + nl) * 128 + o] = fmaxf(val, 0.0f);
                sigL[nl][o] = sigmoidf_(val);
            }
        }
    }
    __syncthreads();

    // ---- gate = sigmoid(sr) @ W_vosf + b_vosf : 256-thread partials ----
    {
        const float* sp = &sigL[nn][h * 8];
        float4 s0 = *(const float4*)sp;
        float4 s1 = *(const float4*)(sp + 4);
        float sv[8] = {s0.x, s0.y, s0.z, s0.w, s1.x, s1.y, s1.z, s1.w};
        float p[9];
#pragma unroll
        for (int k = 0; k < 9; k++) p[k] = 0.f;
#pragma unroll
        for (int i = 0; i < 8; i++) {
            int o = h * 8 + i;
#pragma unroll
            for (int k = 0; k < 9; k++) p[k] += sv[i] * W_vosf[o * 9 + k];
        }
#pragma unroll
        for (int k = 0; k < 9; k++) redL[nn][h][k] = p[k];
    }
    __syncthreads();
    if (h < 9) {
        float a = b_vosf[h];
#pragma unroll
        for (int j = 0; j < 16; j++) a += redL[nn][j][h];
        gateL[nn][h] = a;
    }
    __syncthreads();

    // ---- phase 3: vector path ----
    {
        int o = h;  // VO index
        float gv[9];
#pragma unroll
        for (int i = 0; i < 3; i++)
#pragma unroll
            for (int kk = 0; kk < 3; kk++) {
                float a = 0.f;
#pragma unroll
                for (int j = 0; j < 3; j++) a += gateL[nn][j * 3 + i] * FbarL[nn][j * 3 + kk];
                gv[i * 3 + kk] = a;
            }
        float gvr[3];
#pragma unroll
        for (int kk = 0; kk < 3; kk++) {
            float a = 0.f;
#pragma unroll
            for (int i = 0; i < 3; i++) a += gv[i * 3 + kk] * W_vuf[i * 16 + o];
            gvr[kk] = a;
        }
        float gn2 = sqrtf(gvr[0] * gvr[0] + gvr[1] * gvr[1] + gvr[2] * gvr[2] + EPSV);
        float sg = sigmoidf_(gn2);
#pragma unroll
        for (int c = 0; c < 3; c++) {
            float a = 0.f;
#pragma unroll
            for (int h2 = 0; h2 < 16; h2++) a += vhL[nn][c][h2] * W_vu[h2 * 16 + o];
            out1[(size_t)n * 48 + o * 3 + c] = a * sg;
        }
    }
}

extern "C" void kernel_launch(void* const* d_in, const int* in_sizes, int n_in,
                              void* d_out, int out_size, void* d_ws, size_t ws_size,
                              hipStream_t stream) {
    const float* s      = (const float*)d_in[0];
    const float* v      = (const float*)d_in[1];
    const float* frames = (const float*)d_in[2];
    const float* W_vd   = (const float*)d_in[3];
    const float* W_vdf  = (const float*)d_in[4];
    const float* W_so   = (const float*)d_in[5];
    const float* b_so   = (const float*)d_in[6];
    const float* W_vu   = (const float*)d_in[7];
    const float* W_vosf = (const float*)d_in[8];
    const float* b_vosf = (const float*)d_in[9];
    const float* W_vuf  = (const float*)d_in[10];
    const int* edge_index = (const int*)d_in[11];
    // d_in[12] = node_inputs (assumed truthy, per reference)

    // ws: head[50K int] | next[1.6M int] | Whi[160*128 s16] | Wlo[160*128 s16]
    const size_t head_b = (size_t)N_NODES * sizeof(int);          // 200 KB
    const size_t next_b = (size_t)N_EDGES * sizeof(int);          // 6.4 MB
    int*   head = (int*)d_ws;
    int*   nxt  = (int*)((char*)d_ws + head_b);
    short* Whi  = (short*)((char*)d_ws + head_b + next_b);
    short* Wlo  = Whi + 160 * 128;
    float* out0 = (float*)d_out;
    float* out1 = out0 + (size_t)N_NODES * 128;

    hipMemsetAsync(head, 0xFF, head_b, stream);  // head[n] = -1
    prep_w_kernel<<<(160 * 128 + 255) / 256, 256, 0, stream>>>(W_so, Whi, Wlo);
    bucket_kernel<<<(N_EDGES + 255) / 256, 256, 0, stream>>>(edge_index, head, nxt);
    node_kernel<<<N_NODES / NPB, 256, 0, stream>>>(
        s, v, frames, W_vd, W_vdf, Whi, Wlo, b_so, W_vu, W_vosf, b_vosf, W_vuf,
        head, nxt, out0, out1);
}